// Round 4
// baseline (645.564 us; speedup 1.0000x reference)
//
#include <hip/hip_runtime.h>
#include <hip/hip_bf16.h>

// FeatureAttention on MI355X — Round 4: dbuf GEMM K-loop (1 barrier/step,
// prefetch-before-compute) + conflict-free fragment-order LDS layout
// (pre-swizzled global source, linear ds_read_b128).
// Pipeline: wconvT(x5) -> LN1 -> fused QKV GEMM -> attn(+LN2) -> FFN1 -> FFN2.

#define D_DIM 512
#define NROWS 32768
#define NBE   512

typedef __attribute__((ext_vector_type(8))) short bf16x8;
typedef __attribute__((ext_vector_type(4))) float f32x4;

typedef const __attribute__((address_space(1))) unsigned g_u32;
typedef __attribute__((address_space(3))) unsigned lds_u32;

__device__ __forceinline__ short f2bf(float f) {
  union { float f; unsigned u; } c; c.f = f;
  unsigned u = c.u;
  unsigned r = (u + 0x7FFFu + ((u >> 16) & 1u)) >> 16;   // RNE
  return (short)r;
}
__device__ __forceinline__ float bf2f(short s) {
  union { unsigned u; float f; } c; c.u = ((unsigned)(unsigned short)s) << 16;
  return c.f;
}

// ---- LDS-tiled transpose + fp32->bf16: Wt[n][k] = bf16(W[k][n]) ----
__global__ __launch_bounds__(256) void wconvT(const float* __restrict__ W,
                                              short* __restrict__ Wt,
                                              int K, int N) {
  __shared__ float tile[32][33];
  const int t = threadIdx.x;
  const int r  = t >> 3;            // 0..31
  const int c4 = (t & 7) * 4;       // 0,4,...,28
  const long k0 = (long)blockIdx.y * 32;
  const long n0 = (long)blockIdx.x * 32;
  float4 v = *(const float4*)&W[(k0 + r) * N + n0 + c4];
  tile[r][c4 + 0] = v.x; tile[r][c4 + 1] = v.y;
  tile[r][c4 + 2] = v.z; tile[r][c4 + 3] = v.w;
  __syncthreads();
  union { short sh[4]; int2 v; } o;
#pragma unroll
  for (int j = 0; j < 4; ++j) o.sh[j] = f2bf(tile[c4 + j][r]);
  *(int2*)&Wt[(n0 + r) * K + k0 + c4] = o.v;
}

// ---- LayerNorm over D=512, fp32 in -> bf16 out. One wave per row. ----
__global__ __launch_bounds__(256) void ln_kernel(const float* __restrict__ x,
                                                 const float* __restrict__ gam,
                                                 const float* __restrict__ bet,
                                                 short* __restrict__ h) {
  const int t = threadIdx.x;
  const long row = (long)blockIdx.x * 4 + (t >> 6);
  const int lane = t & 63;
  const float* xr = x + row * D_DIM + lane * 8;
  float4 a = *(const float4*)xr;
  float4 b = *(const float4*)(xr + 4);
  float xs[8] = {a.x, a.y, a.z, a.w, b.x, b.y, b.z, b.w};
  float s = 0.f, ss = 0.f;
#pragma unroll
  for (int j = 0; j < 8; ++j) { s += xs[j]; ss += xs[j] * xs[j]; }
#pragma unroll
  for (int m = 1; m < 64; m <<= 1) {
    s  += __shfl_xor(s, m);
    ss += __shfl_xor(ss, m);
  }
  float mean = s * (1.f / D_DIM);
  float var  = ss * (1.f / D_DIM) - mean * mean;
  float rstd = rsqrtf(var + 1e-5f);
  union { short sh[8]; int4 v; } o;
#pragma unroll
  for (int j = 0; j < 8; ++j) {
    int d = lane * 8 + j;
    o.sh[j] = f2bf((xs[j] - mean) * rstd * gam[d] + bet[d]);
  }
  *(int4*)&h[row * D_DIM + lane * 8] = o.v;
}

// ---- dbuf bf16 MFMA GEMM, XCD-chunked swizzle, fragment-order LDS ----
// out[M,N] = A[M,K] @ Bt[N,K]^T + bias (+resid). 128x128 tile, 4 waves 2x2,
// each wave 64x64 = 4x4 16x16x32 frags. BK=32.
// LDS layout per 16-row chunk c: byte c*1024 + l*16 holds
// (row = c*16 + (l&15), k-slot = l>>4) -> ds_read_b128 is 1KB linear,
// bank-conflict-free. Achieved by permuting the per-lane GLOBAL src addr
// (global_load_lds dest is wave-uniform base + lane*16).
// K-loop: double-buffered, prefetch next tile before compute, ONE barrier
// per step (implicit vmcnt(0)+lgkmcnt(0) drain at the barrier).
template <int OUT_BF16, int RESID>
__global__ __launch_bounds__(256) void gemm128(
    const short* __restrict__ A, const short* __restrict__ Bt,
    const float* __restrict__ bias0, const float* __restrict__ bias1,
    const float* __restrict__ bias2,
    void* __restrict__ out0, void* __restrict__ out1, void* __restrict__ out2,
    const float* __restrict__ resid, int K, int nsplit) {
  __shared__ short As[2][8 * 512];   // 2 x 8KB
  __shared__ short Bs[2][8 * 512];   // 2 x 8KB
  const int t = threadIdx.x;
  const int wave = t >> 6, lane = t & 63;
  const int lr = lane & 15, g = lane >> 4;
  const int wr = wave >> 1, wc = wave & 1;

  // XCD-chunked bijective swizzle (T1). nwg % 8 == 0 for all our grids.
  const int gx = gridDim.x;
  const int nwg = gx * gridDim.y;
  const int hid = blockIdx.y * gx + blockIdx.x;
  const int lid = (hid & 7) * (nwg >> 3) + (hid >> 3);
  const int m0 = (lid / gx) * 128;
  const int n0 = (lid % gx) * 128;

  const int seg = n0 / nsplit;                  // block-uniform
  const int ncol0 = n0 - seg * nsplit;
  const float* bias = seg == 0 ? bias0 : (seg == 1 ? bias1 : bias2);
  void* outp = seg == 0 ? out0 : (seg == 1 ? out1 : out2);

  // staging: wave w owns chunks 2w, 2w+1 of A and of B.
  // lane -> global (row = c*16 + (lane&15), kcol = (lane>>4)*8)
  const int srow = lane & 15;
  const int scol = (lane >> 4) * 8;
  const short* gA0 = &A[(long)(m0 + wave * 32 + srow) * K + scol];
  const short* gB0 = &Bt[(long)(n0 + wave * 32 + srow) * K + scol];
  const long rstep = 16L * K;                    // second chunk: +16 rows

  const int nsteps = K >> 5;
  int cur = 0;

#define STAGE(bufi, kk)                                                        \
  do {                                                                         \
    __builtin_amdgcn_global_load_lds((g_u32*)(gA0 + (kk)),                     \
        (lds_u32*)&As[bufi][(wave * 2) * 512], 16, 0, 0);                      \
    __builtin_amdgcn_global_load_lds((g_u32*)(gA0 + rstep + (kk)),             \
        (lds_u32*)&As[bufi][(wave * 2 + 1) * 512], 16, 0, 0);                  \
    __builtin_amdgcn_global_load_lds((g_u32*)(gB0 + (kk)),                     \
        (lds_u32*)&Bs[bufi][(wave * 2) * 512], 16, 0, 0);                      \
    __builtin_amdgcn_global_load_lds((g_u32*)(gB0 + rstep + (kk)),             \
        (lds_u32*)&Bs[bufi][(wave * 2 + 1) * 512], 16, 0, 0);                  \
  } while (0)

  f32x4 acc[4][4];
  const f32x4 vzero = {0.f, 0.f, 0.f, 0.f};
#pragma unroll
  for (int mi = 0; mi < 4; ++mi)
#pragma unroll
    for (int ni = 0; ni < 4; ++ni) acc[mi][ni] = vzero;

  STAGE(0, 0);
  __syncthreads();                         // vmcnt(0) drain + barrier

  const int fo = lane * 8;                 // short offset within chunk
  for (int st = 0; st < nsteps; ++st) {
    if (st + 1 < nsteps) STAGE(cur ^ 1, (st + 1) * 32);   // prefetch next
    const short* sA = &As[cur][0];
    const short* sB = &Bs[cur][0];
    bf16x8 af[4], bfr[4];
#pragma unroll
    for (int mi = 0; mi < 4; ++mi)
      af[mi] = *(const bf16x8*)&sA[(wr * 4 + mi) * 512 + fo];
#pragma unroll
    for (int ni = 0; ni < 4; ++ni)
      bfr[ni] = *(const bf16x8*)&sB[(wc * 4 + ni) * 512 + fo];
#pragma unroll
    for (int mi = 0; mi < 4; ++mi)
#pragma unroll
      for (int ni = 0; ni < 4; ++ni)
        acc[mi][ni] = __builtin_amdgcn_mfma_f32_16x16x32_bf16(af[mi], bfr[ni], acc[mi][ni], 0, 0, 0);
    if (st + 1 < nsteps) {
      __syncthreads();                     // prefetch landed; reads done
      cur ^= 1;
    }
  }
#undef STAGE

  // C/D layout: col = lane&15, row = 4*(lane>>4) + reg
#pragma unroll
  for (int ni = 0; ni < 4; ++ni) {
    const int col = ncol0 + wc * 64 + ni * 16 + lr;
    const float bv = bias[col];
#pragma unroll
    for (int mi = 0; mi < 4; ++mi) {
#pragma unroll
      for (int r = 0; r < 4; ++r) {
        const long row = m0 + wr * 64 + mi * 16 + g * 4 + r;
        float val = acc[mi][ni][r] + bv;
        if (RESID) val += resid[row * (long)nsplit + col];
        if (OUT_BF16) ((short*)outp)[row * (long)nsplit + col] = f2bf(val);
        else          ((float*)outp)[row * (long)nsplit + col] = val;
      }
    }
  }
}

// ---- fused feature attention + residual + LN2, one block per (b,e) ----
__global__ __launch_bounds__(256) void attn_kernel(
    const short* __restrict__ q, const short* __restrict__ k,
    const short* __restrict__ v, const float* __restrict__ x,
    const float* __restrict__ wn_g, const float* __restrict__ wn_b,
    const float* __restrict__ ln2_g, const float* __restrict__ ln2_b,
    float* __restrict__ x1, short* __restrict__ h2) {
  __shared__ float att_s[64][68];
  const int t = threadIdx.x;
  const int wave = t >> 6, lane = t & 63;
  const int lr = lane & 15, g = lane >> 4;
  const long base = (long)blockIdx.x * 64;
  const long qoff = base * D_DIM;

  const f32x4 vzero = {0.f, 0.f, 0.f, 0.f};
  f32x4 acc[4];
#pragma unroll
  for (int nt = 0; nt < 4; ++nt) acc[nt] = vzero;

  for (int ks = 0; ks < 16; ++ks) {
    const int kc = ks * 32 + g * 8;
    bf16x8 afr = *(const bf16x8*)&q[qoff + (long)(wave * 16 + lr) * D_DIM + kc];
#pragma unroll
    for (int nt = 0; nt < 4; ++nt) {
      bf16x8 bfr = *(const bf16x8*)&k[qoff + (long)(nt * 16 + lr) * D_DIM + kc];
      acc[nt] = __builtin_amdgcn_mfma_f32_16x16x32_bf16(afr, bfr, acc[nt], 0, 0, 0);
    }
  }

  const float scale = 0.044194173824159216f;  // 1/sqrt(512)
#pragma unroll
  for (int r = 0; r < 4; ++r) {
    float s = 0.f, ss = 0.f;
#pragma unroll
    for (int nt = 0; nt < 4; ++nt) { float e = acc[nt][r]; s += e; ss += e * e; }
#pragma unroll
    for (int m = 1; m < 16; m <<= 1) { s += __shfl_xor(s, m); ss += __shfl_xor(ss, m); }
    float mean = s * (1.f / 64);
    float var  = ss * (1.f / 64) - mean * mean;
    float rstd = rsqrtf(var + 1e-5f);
    float e[4]; float mx = -1e30f;
#pragma unroll
    for (int nt = 0; nt < 4; ++nt) {
      int col = nt * 16 + lr;
      e[nt] = ((acc[nt][r] - mean) * rstd * wn_g[col] + wn_b[col]) * scale;
      mx = fmaxf(mx, e[nt]);
    }
#pragma unroll
    for (int m = 1; m < 16; m <<= 1) mx = fmaxf(mx, __shfl_xor(mx, m));
    float se = 0.f;
#pragma unroll
    for (int nt = 0; nt < 4; ++nt) { e[nt] = expf(e[nt] - mx); se += e[nt]; }
#pragma unroll
    for (int m = 1; m < 16; m <<= 1) se += __shfl_xor(se, m);
    float inv = 1.f / se;
#pragma unroll
    for (int nt = 0; nt < 4; ++nt)
      att_s[wave * 16 + 4 * g + r][nt * 16 + lr] = e[nt] * inv;
  }
  __syncthreads();

  const int d0 = lane * 8;
  float accp[16][8];
#pragma unroll
  for (int qi = 0; qi < 16; ++qi)
#pragma unroll
    for (int j = 0; j < 8; ++j) accp[qi][j] = 0.f;

  for (int kk0 = 0; kk0 < 64; kk0 += 4) {
    float vf[4][8];
#pragma unroll
    for (int kc = 0; kc < 4; ++kc) {
      bf16x8 vv = *(const bf16x8*)&v[qoff + (long)(kk0 + kc) * D_DIM + d0];
#pragma unroll
      for (int j = 0; j < 8; ++j) vf[kc][j] = bf2f(vv[j]);
    }
#pragma unroll
    for (int qi = 0; qi < 16; ++qi) {
      float4 a4 = *(const float4*)&att_s[wave * 16 + qi][kk0];
#pragma unroll
      for (int j = 0; j < 8; ++j) {
        accp[qi][j] += a4.x * vf[0][j];
        accp[qi][j] += a4.y * vf[1][j];
        accp[qi][j] += a4.z * vf[2][j];
        accp[qi][j] += a4.w * vf[3][j];
      }
    }
  }

  float g2v[8], b2v[8];
#pragma unroll
  for (int j = 0; j < 8; ++j) { g2v[j] = ln2_g[d0 + j]; b2v[j] = ln2_b[d0 + j]; }

#pragma unroll
  for (int qi = 0; qi < 16; ++qi) {
    const long row = base + wave * 16 + qi;
    const float* xr = x + row * D_DIM + d0;
    float4 x0 = *(const float4*)xr;
    float4 xb = *(const float4*)(xr + 4);
    accp[qi][0] += x0.x; accp[qi][1] += x0.y;
    accp[qi][2] += x0.z; accp[qi][3] += x0.w;
    accp[qi][4] += xb.x; accp[qi][5] += xb.y;
    accp[qi][6] += xb.z; accp[qi][7] += xb.w;
    float* po = x1 + row * D_DIM + d0;
    *(float4*)po       = make_float4(accp[qi][0], accp[qi][1], accp[qi][2], accp[qi][3]);
    *(float4*)(po + 4) = make_float4(accp[qi][4], accp[qi][5], accp[qi][6], accp[qi][7]);
    float s = 0.f, ss = 0.f;
#pragma unroll
    for (int j = 0; j < 8; ++j) { s += accp[qi][j]; ss += accp[qi][j] * accp[qi][j]; }
#pragma unroll
    for (int m = 1; m < 64; m <<= 1) { s += __shfl_xor(s, m); ss += __shfl_xor(ss, m); }
    float mean = s * (1.f / D_DIM);
    float var  = ss * (1.f / D_DIM) - mean * mean;
    float rstd = rsqrtf(var + 1e-5f);
    union { short sh[8]; int4 v; } o;
#pragma unroll
    for (int j = 0; j < 8; ++j)
      o.sh[j] = f2bf((accp[qi][j] - mean) * rstd * g2v[j] + b2v[j]);
    *(int4*)&h2[row * D_DIM + d0] = o.v;
  }
}

extern "C" void kernel_launch(void* const* d_in, const int* in_sizes, int n_in,
                              void* d_out, int out_size, void* d_ws, size_t ws_size,
                              hipStream_t stream) {
  (void)in_sizes; (void)n_in; (void)out_size; (void)ws_size;
  const float* x     = (const float*)d_in[0];
  const float* ln1_g = (const float*)d_in[1];
  const float* ln1_b = (const float*)d_in[2];
  const float* Wq    = (const float*)d_in[3];
  const float* bq    = (const float*)d_in[4];
  const float* Wk    = (const float*)d_in[5];
  const float* bk    = (const float*)d_in[6];
  const float* Wv    = (const float*)d_in[7];
  const float* bv    = (const float*)d_in[8];
  const float* wn_g  = (const float*)d_in[9];
  const float* wn_b  = (const float*)d_in[10];
  const float* ln2_g = (const float*)d_in[11];
  const float* ln2_b = (const float*)d_in[12];
  const float* W1    = (const float*)d_in[13];
  const float* b1    = (const float*)d_in[14];
  const float* W2    = (const float*)d_in[15];
  const float* b2    = (const float*)d_in[16];
  float* out = (float*)d_out;

  char* ws = (char*)d_ws;
  short* h   = (short*)(ws);                                  // 32 MB (h, then h2)
  short* qb  = (short*)(ws + (size_t)32  * 1024 * 1024);      // 32 MB
  short* kb  = (short*)(ws + (size_t)64  * 1024 * 1024);      // 32 MB
  short* vb  = (short*)(ws + (size_t)96  * 1024 * 1024);      // 32 MB
  short* ff1 = (short*)(ws + (size_t)32  * 1024 * 1024);      // 128 MB, aliases dead q/k/v
  short* Wqt = (short*)(ws + (size_t)160 * 1024 * 1024);      // [1536][512] contiguous qkv
  short* Wkt = Wqt + 512 * 512;
  short* Wvt = Wkt + 512 * 512;
  short* W1t = Wvt + 512 * 512;                               // [2048][512]
  short* W2t = W1t + 512 * 2048;                              // [512][2048]

  wconvT<<<dim3(512 / 32, 512 / 32),  256, 0, stream>>>(Wq, Wqt, 512, 512);
  wconvT<<<dim3(512 / 32, 512 / 32),  256, 0, stream>>>(Wk, Wkt, 512, 512);
  wconvT<<<dim3(512 / 32, 512 / 32),  256, 0, stream>>>(Wv, Wvt, 512, 512);
  wconvT<<<dim3(2048 / 32, 512 / 32), 256, 0, stream>>>(W1, W1t, 512, 2048);
  wconvT<<<dim3(512 / 32, 2048 / 32), 256, 0, stream>>>(W2, W2t, 2048, 512);

  ln_kernel<<<NROWS / 4, 256, 0, stream>>>(x, ln1_g, ln1_b, h);

  dim3 gqkv(1536 / 128, NROWS / 128);   // (12, 256) = 3072 blocks
  gemm128<1, 0><<<gqkv, 256, 0, stream>>>(h, Wqt, bq, bk, bv,
                                          qb, kb, vb, nullptr, 512, 512);

  attn_kernel<<<NBE, 256, 0, stream>>>(qb, kb, vb, x, wn_g, wn_b,
                                       ln2_g, ln2_b, out, h);

  dim3 gff1(2048 / 128, NROWS / 128);   // (16, 256) = 4096 blocks
  gemm128<1, 0><<<gff1, 256, 0, stream>>>(h, W1t, b1, b1, b1,
                                          ff1, ff1, ff1, nullptr, 512, 2048);

  dim3 gff2(512 / 128, NROWS / 128);    // (4, 256) = 1024 blocks
  gemm128<0, 1><<<gff2, 256, 0, stream>>>(ff1, W2t, b2, b2, b2,
                                          out, out, out, out, 2048, 512);
}

// Round 5
// 543.235 us; speedup vs baseline: 1.1884x; 1.1884x over previous
//
#include <hip/hip_runtime.h>
#include <hip/hip_bf16.h>

// FeatureAttention on MI355X — Round 5: 256x256 GEMM with counted-vmcnt
// pipeline (T3+T4+T5): 3-deep LDS ring, prefetch distance 2 K-tiles,
// s_waitcnt vmcnt(4) gate once per K-tile (never drain-0 in loop), raw
// s_barrier, setprio around MFMA clusters, fragment-order conflict-free LDS.
// Pipeline: wconvT(x5) -> LN1 -> fused QKV GEMM -> attn(+LN2) -> FFN1 -> FFN2.

#define D_DIM 512
#define NROWS 32768
#define NBE   512

typedef __attribute__((ext_vector_type(8))) short bf16x8;
typedef __attribute__((ext_vector_type(4))) float f32x4;

typedef const __attribute__((address_space(1))) unsigned g_u32;
typedef __attribute__((address_space(3))) unsigned lds_u32;

__device__ __forceinline__ short f2bf(float f) {
  union { float f; unsigned u; } c; c.f = f;
  unsigned u = c.u;
  unsigned r = (u + 0x7FFFu + ((u >> 16) & 1u)) >> 16;   // RNE
  return (short)r;
}
__device__ __forceinline__ float bf2f(short s) {
  union { unsigned u; float f; } c; c.u = ((unsigned)(unsigned short)s) << 16;
  return c.f;
}

// ---- LDS-tiled transpose + fp32->bf16: Wt[n][k] = bf16(W[k][n]) ----
__global__ __launch_bounds__(256) void wconvT(const float* __restrict__ W,
                                              short* __restrict__ Wt,
                                              int K, int N) {
  __shared__ float tile[32][33];
  const int t = threadIdx.x;
  const int r  = t >> 3;            // 0..31
  const int c4 = (t & 7) * 4;       // 0,4,...,28
  const long k0 = (long)blockIdx.y * 32;
  const long n0 = (long)blockIdx.x * 32;
  float4 v = *(const float4*)&W[(k0 + r) * N + n0 + c4];
  tile[r][c4 + 0] = v.x; tile[r][c4 + 1] = v.y;
  tile[r][c4 + 2] = v.z; tile[r][c4 + 3] = v.w;
  __syncthreads();
  union { short sh[4]; int2 v; } o;
#pragma unroll
  for (int j = 0; j < 4; ++j) o.sh[j] = f2bf(tile[c4 + j][r]);
  *(int2*)&Wt[(n0 + r) * K + k0 + c4] = o.v;
}

// ---- LayerNorm over D=512, fp32 in -> bf16 out. One wave per row. ----
__global__ __launch_bounds__(256) void ln_kernel(const float* __restrict__ x,
                                                 const float* __restrict__ gam,
                                                 const float* __restrict__ bet,
                                                 short* __restrict__ h) {
  const int t = threadIdx.x;
  const long row = (long)blockIdx.x * 4 + (t >> 6);
  const int lane = t & 63;
  const float* xr = x + row * D_DIM + lane * 8;
  float4 a = *(const float4*)xr;
  float4 b = *(const float4*)(xr + 4);
  float xs[8] = {a.x, a.y, a.z, a.w, b.x, b.y, b.z, b.w};
  float s = 0.f, ss = 0.f;
#pragma unroll
  for (int j = 0; j < 8; ++j) { s += xs[j]; ss += xs[j] * xs[j]; }
#pragma unroll
  for (int m = 1; m < 64; m <<= 1) {
    s  += __shfl_xor(s, m);
    ss += __shfl_xor(ss, m);
  }
  float mean = s * (1.f / D_DIM);
  float var  = ss * (1.f / D_DIM) - mean * mean;
  float rstd = rsqrtf(var + 1e-5f);
  union { short sh[8]; int4 v; } o;
#pragma unroll
  for (int j = 0; j < 8; ++j) {
    int d = lane * 8 + j;
    o.sh[j] = f2bf((xs[j] - mean) * rstd * gam[d] + bet[d]);
  }
  *(int4*)&h[row * D_DIM + lane * 8] = o.v;
}

// ---- 256x256 counted-vmcnt pipelined bf16 MFMA GEMM ----
// out[M,N] = A[M,K] @ Bt[N,K]^T + bias (+resid). 512 threads = 8 waves (2x4),
// each wave owns 128x64 = 8x4 16x16x32 frags. BK=32, K-tile = A 16KB + B 16KB.
// LDS ring: 3 buffers (96 KB dynamic). Prefetch distance 2 tiles; per wave
// 4 gload_lds per tile (2/phase), gate s_waitcnt vmcnt(4) once per tile.
// Fragment-order LDS: chunk r (16 rows x 32 cols, 1KB) stores lane l ->
// (row=r*16+(l&15), k=(l>>4)*8) at byte r*1024 + l*16 -> ds_read_b128 linear,
// bank-conflict-free (measured 0 in R4). Pre-swizzled global src (rule #21).
template <int OUT_BF16, int RESID>
__global__ __launch_bounds__(512, 2) void gemm256(
    const short* __restrict__ A, const short* __restrict__ Bt,
    const float* __restrict__ bias0, const float* __restrict__ bias1,
    const float* __restrict__ bias2,
    void* __restrict__ out0, void* __restrict__ out1, void* __restrict__ out2,
    const float* __restrict__ resid, int K, int nsplit) {
  extern __shared__ short smem[];           // [3][8192] A + [3][8192] B shorts
  short* As = smem;
  short* Bs = smem + 3 * 8192;

  const int t = threadIdx.x;
  const int wave = t >> 6, lane = t & 63;
  const int lr = lane & 15, g = lane >> 4;
  const int wr = wave >> 2, wc = wave & 3;   // 2 x 4 wave grid

  // XCD-chunked bijective swizzle (T1); nwg % 8 == 0 for all our grids.
  const int gx = gridDim.x;
  const int nwg = gx * gridDim.y;
  const int hid = blockIdx.y * gx + blockIdx.x;
  const int lid = (hid & 7) * (nwg >> 3) + (hid >> 3);
  const int m0 = (lid / gx) * 256;
  const int n0 = (lid % gx) * 256;

  const int seg = n0 / nsplit;               // block-uniform
  const int ncol0 = n0 - seg * nsplit;
  const float* bias = seg == 0 ? bias0 : (seg == 1 ? bias1 : bias2);
  void* outp = seg == 0 ? out0 : (seg == 1 ? out1 : out2);

  // staging: wave w owns chunks 2w, 2w+1 of A and of B (rows w*32..w*32+31)
  const int srow = lane & 15;
  const int scol = (lane >> 4) * 8;
  const short* gA0 = &A[(long)(m0 + wave * 32 + srow) * K + scol];
  const short* gB0 = &Bt[(long)(n0 + wave * 32 + srow) * K + scol];
  const long rstep = 16L * K;

#define STAGE_A(bufi, kk)                                                      \
  do {                                                                         \
    __builtin_amdgcn_global_load_lds((g_u32*)(gA0 + (kk)),                     \
        (lds_u32*)(As + (bufi) * 8192 + (wave * 2) * 512), 16, 0, 0);          \
    __builtin_amdgcn_global_load_lds((g_u32*)(gA0 + rstep + (kk)),             \
        (lds_u32*)(As + (bufi) * 8192 + (wave * 2 + 1) * 512), 16, 0, 0);      \
  } while (0)
#define STAGE_B(bufi, kk)                                                      \
  do {                                                                         \
    __builtin_amdgcn_global_load_lds((g_u32*)(gB0 + (kk)),                     \
        (lds_u32*)(Bs + (bufi) * 8192 + (wave * 2) * 512), 16, 0, 0);          \
    __builtin_amdgcn_global_load_lds((g_u32*)(gB0 + rstep + (kk)),             \
        (lds_u32*)(Bs + (bufi) * 8192 + (wave * 2 + 1) * 512), 16, 0, 0);      \
  } while (0)

  f32x4 acc[8][4];
  const f32x4 vzero = {0.f, 0.f, 0.f, 0.f};
#pragma unroll
  for (int mi = 0; mi < 8; ++mi)
#pragma unroll
    for (int ni = 0; ni < 4; ++ni) acc[mi][ni] = vzero;

  const int nt = K >> 5;
  // prologue: stage tiles 0 and 1 (per-wave FIFO: T0's 4 loads, then T1's 4)
  STAGE_A(0, 0);  STAGE_B(0, 0);
  STAGE_A(1, 32); STAGE_B(1, 32);

  int cur = 0, stg = 2;
  const int fo = lane * 8;                   // 16B lane slot within chunk
  for (int T = 0; T < nt; ++T) {
    // --- gate: tile T's 4 loads landed; tile T+1's 4 stay in flight ---
    if (T < nt - 1) asm volatile("s_waitcnt vmcnt(4)" ::: "memory");
    else            asm volatile("s_waitcnt vmcnt(0)" ::: "memory");
    asm volatile("s_barrier" ::: "memory");

    const short* sA = As + cur * 8192;
    const short* sB = Bs + cur * 8192;
    const int kof = (T + 2) * 32;
    const bool stage_more = (T + 2 < nt);

    // ---- phase 0: af chunks wr*8+0..3, bf chunks wc*4+0..3, 16 MFMA ----
    bf16x8 af[4], bfr[4];
#pragma unroll
    for (int i = 0; i < 4; ++i)
      af[i] = *(const bf16x8*)&sA[(wr * 8 + i) * 512 + fo];
#pragma unroll
    for (int i = 0; i < 4; ++i)
      bfr[i] = *(const bf16x8*)&sB[(wc * 4 + i) * 512 + fo];
    if (stage_more) STAGE_A(stg, kof);
    asm volatile("s_barrier" ::: "memory");
    __builtin_amdgcn_sched_barrier(0);
    __builtin_amdgcn_s_setprio(1);
#pragma unroll
    for (int mi = 0; mi < 4; ++mi)
#pragma unroll
      for (int ni = 0; ni < 4; ++ni)
        acc[mi][ni] = __builtin_amdgcn_mfma_f32_16x16x32_bf16(af[mi], bfr[ni], acc[mi][ni], 0, 0, 0);
    __builtin_amdgcn_s_setprio(0);
    __builtin_amdgcn_sched_barrier(0);
    asm volatile("s_barrier" ::: "memory");

    // ---- phase 1: af chunks wr*8+4..7, reuse bfr, 16 MFMA ----
#pragma unroll
    for (int i = 0; i < 4; ++i)
      af[i] = *(const bf16x8*)&sA[(wr * 8 + 4 + i) * 512 + fo];
    if (stage_more) STAGE_B(stg, kof);
    asm volatile("s_barrier" ::: "memory");
    __builtin_amdgcn_sched_barrier(0);
    __builtin_amdgcn_s_setprio(1);
#pragma unroll
    for (int mi = 0; mi < 4; ++mi)
#pragma unroll
      for (int ni = 0; ni < 4; ++ni)
        acc[4 + mi][ni] = __builtin_amdgcn_mfma_f32_16x16x32_bf16(af[mi], bfr[ni], acc[4 + mi][ni], 0, 0, 0);
    __builtin_amdgcn_s_setprio(0);
    __builtin_amdgcn_sched_barrier(0);
    // (no trailing barrier: next tile's gate barrier covers it)

    cur = cur == 2 ? 0 : cur + 1;
    stg = stg == 2 ? 0 : stg + 1;
  }
#undef STAGE_A
#undef STAGE_B

  // C/D layout: col = lane&15, row = 4*(lane>>4) + reg
#pragma unroll
  for (int ni = 0; ni < 4; ++ni) {
    const int col = ncol0 + wc * 64 + ni * 16 + lr;
    const float bv = bias[col];
#pragma unroll
    for (int mi = 0; mi < 8; ++mi) {
#pragma unroll
      for (int r = 0; r < 4; ++r) {
        const long row = m0 + wr * 128 + mi * 16 + g * 4 + r;
        float val = acc[mi][ni][r] + bv;
        if (RESID) val += resid[row * (long)nsplit + col];
        if (OUT_BF16) ((short*)outp)[row * (long)nsplit + col] = f2bf(val);
        else          ((float*)outp)[row * (long)nsplit + col] = val;
      }
    }
  }
}

// ---- fused feature attention + residual + LN2, one block per (b,e) ----
__global__ __launch_bounds__(256) void attn_kernel(
    const short* __restrict__ q, const short* __restrict__ k,
    const short* __restrict__ v, const float* __restrict__ x,
    const float* __restrict__ wn_g, const float* __restrict__ wn_b,
    const float* __restrict__ ln2_g, const float* __restrict__ ln2_b,
    float* __restrict__ x1, short* __restrict__ h2) {
  __shared__ float att_s[64][68];
  const int t = threadIdx.x;
  const int wave = t >> 6, lane = t & 63;
  const int lr = lane & 15, g = lane >> 4;
  const long base = (long)blockIdx.x * 64;
  const long qoff = base * D_DIM;

  const f32x4 vzero = {0.f, 0.f, 0.f, 0.f};
  f32x4 acc[4];
#pragma unroll
  for (int nt = 0; nt < 4; ++nt) acc[nt] = vzero;

  for (int ks = 0; ks < 16; ++ks) {
    const int kc = ks * 32 + g * 8;
    bf16x8 afr = *(const bf16x8*)&q[qoff + (long)(wave * 16 + lr) * D_DIM + kc];
#pragma unroll
    for (int nt = 0; nt < 4; ++nt) {
      bf16x8 bfr = *(const bf16x8*)&k[qoff + (long)(nt * 16 + lr) * D_DIM + kc];
      acc[nt] = __builtin_amdgcn_mfma_f32_16x16x32_bf16(afr, bfr, acc[nt], 0, 0, 0);
    }
  }

  const float scale = 0.044194173824159216f;  // 1/sqrt(512)
#pragma unroll
  for (int r = 0; r < 4; ++r) {
    float s = 0.f, ss = 0.f;
#pragma unroll
    for (int nt = 0; nt < 4; ++nt) { float e = acc[nt][r]; s += e; ss += e * e; }
#pragma unroll
    for (int m = 1; m < 16; m <<= 1) { s += __shfl_xor(s, m); ss += __shfl_xor(ss, m); }
    float mean = s * (1.f / 64);
    float var  = ss * (1.f / 64) - mean * mean;
    float rstd = rsqrtf(var + 1e-5f);
    float e[4]; float mx = -1e30f;
#pragma unroll
    for (int nt = 0; nt < 4; ++nt) {
      int col = nt * 16 + lr;
      e[nt] = ((acc[nt][r] - mean) * rstd * wn_g[col] + wn_b[col]) * scale;
      mx = fmaxf(mx, e[nt]);
    }
#pragma unroll
    for (int m = 1; m < 16; m <<= 1) mx = fmaxf(mx, __shfl_xor(mx, m));
    float se = 0.f;
#pragma unroll
    for (int nt = 0; nt < 4; ++nt) { e[nt] = expf(e[nt] - mx); se += e[nt]; }
#pragma unroll
    for (int m = 1; m < 16; m <<= 1) se += __shfl_xor(se, m);
    float inv = 1.f / se;
#pragma unroll
    for (int nt = 0; nt < 4; ++nt)
      att_s[wave * 16 + 4 * g + r][nt * 16 + lr] = e[nt] * inv;
  }
  __syncthreads();

  const int d0 = lane * 8;
  float accp[16][8];
#pragma unroll
  for (int qi = 0; qi < 16; ++qi)
#pragma unroll
    for (int j = 0; j < 8; ++j) accp[qi][j] = 0.f;

  for (int kk0 = 0; kk0 < 64; kk0 += 4) {
    float vf[4][8];
#pragma unroll
    for (int kc = 0; kc < 4; ++kc) {
      bf16x8 vv = *(const bf16x8*)&v[qoff + (long)(kk0 + kc) * D_DIM + d0];
#pragma unroll
      for (int j = 0; j < 8; ++j) vf[kc][j] = bf2f(vv[j]);
    }
#pragma unroll
    for (int qi = 0; qi < 16; ++qi) {
      float4 a4 = *(const float4*)&att_s[wave * 16 + qi][kk0];
#pragma unroll
      for (int j = 0; j < 8; ++j) {
        accp[qi][j] += a4.x * vf[0][j];
        accp[qi][j] += a4.y * vf[1][j];
        accp[qi][j] += a4.z * vf[2][j];
        accp[qi][j] += a4.w * vf[3][j];
      }
    }
  }

  float g2v[8], b2v[8];
#pragma unroll
  for (int j = 0; j < 8; ++j) { g2v[j] = ln2_g[d0 + j]; b2v[j] = ln2_b[d0 + j]; }

#pragma unroll
  for (int qi = 0; qi < 16; ++qi) {
    const long row = base + wave * 16 + qi;
    const float* xr = x + row * D_DIM + d0;
    float4 x0 = *(const float4*)xr;
    float4 xb = *(const float4*)(xr + 4);
    accp[qi][0] += x0.x; accp[qi][1] += x0.y;
    accp[qi][2] += x0.z; accp[qi][3] += x0.w;
    accp[qi][4] += xb.x; accp[qi][5] += xb.y;
    accp[qi][6] += xb.z; accp[qi][7] += xb.w;
    float* po = x1 + row * D_DIM + d0;
    *(float4*)po       = make_float4(accp[qi][0], accp[qi][1], accp[qi][2], accp[qi][3]);
    *(float4*)(po + 4) = make_float4(accp[qi][4], accp[qi][5], accp[qi][6], accp[qi][7]);
    float s = 0.f, ss = 0.f;
#pragma unroll
    for (int j = 0; j < 8; ++j) { s += accp[qi][j]; ss += accp[qi][j] * accp[qi][j]; }
#pragma unroll
    for (int m = 1; m < 64; m <<= 1) { s += __shfl_xor(s, m); ss += __shfl_xor(ss, m); }
    float mean = s * (1.f / D_DIM);
    float var  = ss * (1.f / D_DIM) - mean * mean;
    float rstd = rsqrtf(var + 1e-5f);
    union { short sh[8]; int4 v; } o;
#pragma unroll
    for (int j = 0; j < 8; ++j)
      o.sh[j] = f2bf((accp[qi][j] - mean) * rstd * g2v[j] + b2v[j]);
    *(int4*)&h2[row * D_DIM + d0] = o.v;
  }
}

extern "C" void kernel_launch(void* const* d_in, const int* in_sizes, int n_in,
                              void* d_out, int out_size, void* d_ws, size_t ws_size,
                              hipStream_t stream) {
  (void)in_sizes; (void)n_in; (void)out_size; (void)ws_size;
  const float* x     = (const float*)d_in[0];
  const float* ln1_g = (const float*)d_in[1];
  const float* ln1_b = (const float*)d_in[2];
  const float* Wq    = (const float*)d_in[3];
  const float* bq    = (const float*)d_in[4];
  const float* Wk    = (const float*)d_in[5];
  const float* bk    = (const float*)d_in[6];
  const float* Wv    = (const float*)d_in[7];
  const float* bv    = (const float*)d_in[8];
  const float* wn_g  = (const float*)d_in[9];
  const float* wn_b  = (const float*)d_in[10];
  const float* ln2_g = (const float*)d_in[11];
  const float* ln2_b = (const float*)d_in[12];
  const float* W1    = (const float*)d_in[13];
  const float* b1    = (const float*)d_in[14];
  const float* W2    = (const float*)d_in[15];
  const float* b2    = (const float*)d_in[16];
  float* out = (float*)d_out;

  char* ws = (char*)d_ws;
  short* h   = (short*)(ws);                                  // 32 MB (h, then h2)
  short* qb  = (short*)(ws + (size_t)32  * 1024 * 1024);      // 32 MB
  short* kb  = (short*)(ws + (size_t)64  * 1024 * 1024);      // 32 MB
  short* vb  = (short*)(ws + (size_t)96  * 1024 * 1024);      // 32 MB
  short* ff1 = (short*)(ws + (size_t)32  * 1024 * 1024);      // 128 MB, aliases dead q/k/v
  short* Wqt = (short*)(ws + (size_t)160 * 1024 * 1024);      // [1536][512] contiguous qkv
  short* Wkt = Wqt + 512 * 512;
  short* Wvt = Wkt + 512 * 512;
  short* W1t = Wvt + 512 * 512;                               // [2048][512]
  short* W2t = W1t + 512 * 2048;                              // [512][2048]

  const size_t lds_bytes = 3 * 8192 * 2 * 2;                  // 98304 B
  // allow >64KB dynamic LDS (no-op if already permitted)
  (void)hipFuncSetAttribute((const void*)gemm256<1, 0>,
      hipFuncAttributeMaxDynamicSharedMemorySize, (int)lds_bytes);
  (void)hipFuncSetAttribute((const void*)gemm256<0, 1>,
      hipFuncAttributeMaxDynamicSharedMemorySize, (int)lds_bytes);

  wconvT<<<dim3(512 / 32, 512 / 32),  256, 0, stream>>>(Wq, Wqt, 512, 512);
  wconvT<<<dim3(512 / 32, 512 / 32),  256, 0, stream>>>(Wk, Wkt, 512, 512);
  wconvT<<<dim3(512 / 32, 512 / 32),  256, 0, stream>>>(Wv, Wvt, 512, 512);
  wconvT<<<dim3(2048 / 32, 512 / 32), 256, 0, stream>>>(W1, W1t, 512, 2048);
  wconvT<<<dim3(512 / 32, 2048 / 32), 256, 0, stream>>>(W2, W2t, 2048, 512);

  ln_kernel<<<NROWS / 4, 256, 0, stream>>>(x, ln1_g, ln1_b, h);

  dim3 gqkv(1536 / 256, NROWS / 256);   // (6, 128) = 768 blocks
  gemm256<1, 0><<<gqkv, 512, lds_bytes, stream>>>(h, Wqt, bq, bk, bv,
                                                  qb, kb, vb, nullptr, 512, 512);

  attn_kernel<<<NBE, 256, 0, stream>>>(qb, kb, vb, x, wn_g, wn_b,
                                       ln2_g, ln2_b, out, h);

  dim3 gff1(2048 / 256, NROWS / 256);   // (8, 128) = 1024 blocks
  gemm256<1, 0><<<gff1, 512, lds_bytes, stream>>>(h, W1t, b1, b1, b1,
                                                  ff1, ff1, ff1, nullptr, 512, 2048);

  dim3 gff2(512 / 256, NROWS / 256);    // (2, 128) = 256 blocks
  gemm256<0, 1><<<gff2, 512, lds_bytes, stream>>>(ff1, W2t, b2, b2, b2,
                                                  out, out, out, out, 2048, 512);
}

// Round 6
// 507.810 us; speedup vs baseline: 1.2713x; 1.0698x over previous
//
#include <hip/hip_runtime.h>
#include <hip/hip_bf16.h>

// FeatureAttention on MI355X — Round 6: compiler-scheduled K-loop with ONE
// counted-vmcnt gate per K-tile (3-ring LDS, no intra-tile barriers, no
// sched_barrier pinning — m97 interleave + T4 counted gate), plus
// LDS-transpose vectorized C-write epilogue.
// Pipeline: wconvT(x5) -> LN1 -> fused QKV GEMM -> attn(+LN2) -> FFN1 -> FFN2.

#define D_DIM 512
#define NROWS 32768
#define NBE   512

typedef __attribute__((ext_vector_type(8))) short bf16x8;
typedef __attribute__((ext_vector_type(4))) float f32x4;

typedef const __attribute__((address_space(1))) unsigned g_u32;
typedef __attribute__((address_space(3))) unsigned lds_u32;

__device__ __forceinline__ short f2bf(float f) {
  union { float f; unsigned u; } c; c.f = f;
  unsigned u = c.u;
  unsigned r = (u + 0x7FFFu + ((u >> 16) & 1u)) >> 16;   // RNE
  return (short)r;
}
__device__ __forceinline__ float bf2f(short s) {
  union { unsigned u; float f; } c; c.u = ((unsigned)(unsigned short)s) << 16;
  return c.f;
}

// ---- LDS-tiled transpose + fp32->bf16: Wt[n][k] = bf16(W[k][n]) ----
__global__ __launch_bounds__(256) void wconvT(const float* __restrict__ W,
                                              short* __restrict__ Wt,
                                              int K, int N) {
  __shared__ float tile[32][33];
  const int t = threadIdx.x;
  const int r  = t >> 3;            // 0..31
  const int c4 = (t & 7) * 4;       // 0,4,...,28
  const long k0 = (long)blockIdx.y * 32;
  const long n0 = (long)blockIdx.x * 32;
  float4 v = *(const float4*)&W[(k0 + r) * N + n0 + c4];
  tile[r][c4 + 0] = v.x; tile[r][c4 + 1] = v.y;
  tile[r][c4 + 2] = v.z; tile[r][c4 + 3] = v.w;
  __syncthreads();
  union { short sh[4]; int2 v; } o;
#pragma unroll
  for (int j = 0; j < 4; ++j) o.sh[j] = f2bf(tile[c4 + j][r]);
  *(int2*)&Wt[(n0 + r) * K + k0 + c4] = o.v;
}

// ---- LayerNorm over D=512, fp32 in -> bf16 out. One wave per row. ----
__global__ __launch_bounds__(256) void ln_kernel(const float* __restrict__ x,
                                                 const float* __restrict__ gam,
                                                 const float* __restrict__ bet,
                                                 short* __restrict__ h) {
  const int t = threadIdx.x;
  const long row = (long)blockIdx.x * 4 + (t >> 6);
  const int lane = t & 63;
  const float* xr = x + row * D_DIM + lane * 8;
  float4 a = *(const float4*)xr;
  float4 b = *(const float4*)(xr + 4);
  float xs[8] = {a.x, a.y, a.z, a.w, b.x, b.y, b.z, b.w};
  float s = 0.f, ss = 0.f;
#pragma unroll
  for (int j = 0; j < 8; ++j) { s += xs[j]; ss += xs[j] * xs[j]; }
#pragma unroll
  for (int m = 1; m < 64; m <<= 1) {
    s  += __shfl_xor(s, m);
    ss += __shfl_xor(ss, m);
  }
  float mean = s * (1.f / D_DIM);
  float var  = ss * (1.f / D_DIM) - mean * mean;
  float rstd = rsqrtf(var + 1e-5f);
  union { short sh[8]; int4 v; } o;
#pragma unroll
  for (int j = 0; j < 8; ++j) {
    int d = lane * 8 + j;
    o.sh[j] = f2bf((xs[j] - mean) * rstd * gam[d] + bet[d]);
  }
  *(int4*)&h[row * D_DIM + lane * 8] = o.v;
}

// ---- 256x256 bf16 MFMA GEMM, counted-vmcnt gate, compiler-scheduled ----
// out[M,N] = A[M,K] @ Bt[N,K]^T + bias (+resid). 512 threads = 8 waves (2x4),
// each wave 128x64 = 8x4 16x16x32 frags. BK=32. LDS ring: 3 x (16KB A+B).
// Per K-tile: {vmcnt(4) gate + s_barrier} -> issue STAGE(T+2, 4 gload_lds)
// -> 12 ds_read_b128 + 32 MFMA, fully compiler-scheduled (fine lgkmcnt).
// Ring safety: writes target buf (T+2)%3, readers of that buf's prior data
// finished before this tile's gate barrier; issue is after the barrier.
// Fragment-order LDS (R4/R5: zero bank conflicts): chunk c = 16 rows x 32
// cols at byte c*1024; lane l -> (row=c*16+(l&15), k=(l>>4)*8).
// Epilogue: acc -> wave-private padded LDS (16x68 f32) -> row-major
// vectorized global stores (32B/lane bf16, 64B/lane f32).
template <int OUT_BF16, int RESID>
__global__ __launch_bounds__(512, 2) void gemm256(
    const short* __restrict__ A, const short* __restrict__ Bt,
    const float* __restrict__ bias0, const float* __restrict__ bias1,
    const float* __restrict__ bias2,
    void* __restrict__ out0, void* __restrict__ out1, void* __restrict__ out2,
    const float* __restrict__ resid, int K, int nsplit) {
  extern __shared__ short smem[];           // [3][8192] A + [3][8192] B shorts
  short* As = smem;
  short* Bs = smem + 3 * 8192;

  const int t = threadIdx.x;
  const int wave = t >> 6, lane = t & 63;
  const int lr = lane & 15, g = lane >> 4;
  const int wr = wave >> 2, wc = wave & 3;   // 2 x 4 wave grid

  // XCD-chunked bijective swizzle (T1); nwg % 8 == 0 for all our grids.
  const int gx = gridDim.x;
  const int nwg = gx * gridDim.y;
  const int hid = blockIdx.y * gx + blockIdx.x;
  const int lid = (hid & 7) * (nwg >> 3) + (hid >> 3);
  const int m0 = (lid / gx) * 256;
  const int n0 = (lid % gx) * 256;

  const int seg = n0 / nsplit;               // block-uniform
  const int ncol0 = n0 - seg * nsplit;
  const float* bias = seg == 0 ? bias0 : (seg == 1 ? bias1 : bias2);
  void* outp = seg == 0 ? out0 : (seg == 1 ? out1 : out2);

  // staging: wave w owns chunks 2w, 2w+1 of A and of B (rows w*32..w*32+31)
  const int srow = lane & 15;
  const int scol = (lane >> 4) * 8;
  const short* gA0 = &A[(long)(m0 + wave * 32 + srow) * K + scol];
  const short* gB0 = &Bt[(long)(n0 + wave * 32 + srow) * K + scol];
  const long rstep = 16L * K;

#define STAGE_A(bufi, kk)                                                      \
  do {                                                                         \
    __builtin_amdgcn_global_load_lds((g_u32*)(gA0 + (kk)),                     \
        (lds_u32*)(As + (bufi) * 8192 + (wave * 2) * 512), 16, 0, 0);          \
    __builtin_amdgcn_global_load_lds((g_u32*)(gA0 + rstep + (kk)),             \
        (lds_u32*)(As + (bufi) * 8192 + (wave * 2 + 1) * 512), 16, 0, 0);      \
  } while (0)
#define STAGE_B(bufi, kk)                                                      \
  do {                                                                         \
    __builtin_amdgcn_global_load_lds((g_u32*)(gB0 + (kk)),                     \
        (lds_u32*)(Bs + (bufi) * 8192 + (wave * 2) * 512), 16, 0, 0);          \
    __builtin_amdgcn_global_load_lds((g_u32*)(gB0 + rstep + (kk)),             \
        (lds_u32*)(Bs + (bufi) * 8192 + (wave * 2 + 1) * 512), 16, 0, 0);      \
  } while (0)

  f32x4 acc[8][4];
  const f32x4 vzero = {0.f, 0.f, 0.f, 0.f};
#pragma unroll
  for (int mi = 0; mi < 8; ++mi)
#pragma unroll
    for (int ni = 0; ni < 4; ++ni) acc[mi][ni] = vzero;

  const int nt = K >> 5;
  // prologue: stage tiles 0 and 1 (per-wave FIFO order)
  STAGE_A(0, 0);  STAGE_B(0, 0);
  STAGE_A(1, 32); STAGE_B(1, 32);

  int cur = 0, stg = 2;
  const int fo = lane * 8;                   // 16B lane slot within chunk
  for (int T = 0; T < nt; ++T) {
    // gate: tile T's 4 loads landed; tile T+1's 4 may stay in flight
    if (T < nt - 1) asm volatile("s_waitcnt vmcnt(4)" ::: "memory");
    else            asm volatile("s_waitcnt vmcnt(0)" ::: "memory");
    asm volatile("s_barrier" ::: "memory");

    if (T + 2 < nt) {                        // prefetch distance 2
      STAGE_A(stg, (T + 2) * 32);
      STAGE_B(stg, (T + 2) * 32);
    }

    const short* sA = As + cur * 8192;
    const short* sB = Bs + cur * 8192;
    bf16x8 af[8], bfr[4];
#pragma unroll
    for (int i = 0; i < 8; ++i)
      af[i] = *(const bf16x8*)&sA[(wr * 8 + i) * 512 + fo];
#pragma unroll
    for (int i = 0; i < 4; ++i)
      bfr[i] = *(const bf16x8*)&sB[(wc * 4 + i) * 512 + fo];
    // compiler-scheduled: fine-grained lgkmcnt interleave of reads + MFMA
#pragma unroll
    for (int mi = 0; mi < 8; ++mi)
#pragma unroll
      for (int ni = 0; ni < 4; ++ni)
        acc[mi][ni] = __builtin_amdgcn_mfma_f32_16x16x32_bf16(af[mi], bfr[ni], acc[mi][ni], 0, 0, 0);

    cur = cur == 2 ? 0 : cur + 1;
    stg = stg == 2 ? 0 : stg + 1;
  }
#undef STAGE_A
#undef STAGE_B

  // ---- epilogue: LDS-transpose to row-major vectorized stores ----
  __syncthreads();                           // K-loop LDS now reusable
  float* cs = (float*)smem + wave * 1088;    // wave-private 16 x 68 f32
  float bv[4];
#pragma unroll
  for (int ni = 0; ni < 4; ++ni) bv[ni] = bias[ncol0 + wc * 64 + ni * 16 + lr];
  const int er = lane >> 2;                  // 0..15: row within 16-row group
  const int ec = (lane & 3) * 16;            // col block within 64

#pragma unroll
  for (int mi = 0; mi < 8; ++mi) {
#pragma unroll
    for (int ni = 0; ni < 4; ++ni)
#pragma unroll
      for (int r = 0; r < 4; ++r)
        cs[(g * 4 + r) * 68 + ni * 16 + lr] = acc[mi][ni][r] + bv[ni];
    // wave-internal write->read: compiler inserts lgkmcnt
    const long grow = m0 + wr * 128 + mi * 16 + er;
    const long gcol = ncol0 + wc * 64 + ec;
    float vals[16];
#pragma unroll
    for (int jb = 0; jb < 4; ++jb) {
      float4 v = *(const float4*)&cs[er * 68 + ec + jb * 4];
      vals[jb * 4 + 0] = v.x; vals[jb * 4 + 1] = v.y;
      vals[jb * 4 + 2] = v.z; vals[jb * 4 + 3] = v.w;
    }
    if (RESID) {
      const float* rp = resid + grow * (long)nsplit + gcol;
#pragma unroll
      for (int jb = 0; jb < 4; ++jb) {
        float4 v = *(const float4*)&rp[jb * 4];
        vals[jb * 4 + 0] += v.x; vals[jb * 4 + 1] += v.y;
        vals[jb * 4 + 2] += v.z; vals[jb * 4 + 3] += v.w;
      }
    }
    if (OUT_BF16) {
      union { short sh[16]; int4 q[2]; } o;
#pragma unroll
      for (int j = 0; j < 16; ++j) o.sh[j] = f2bf(vals[j]);
      short* op = (short*)outp + grow * (long)nsplit + gcol;
      *(int4*)op = o.q[0];
      *(int4*)(op + 8) = o.q[1];
    } else {
      float* op = (float*)outp + grow * (long)nsplit + gcol;
#pragma unroll
      for (int jb = 0; jb < 4; ++jb)
        *(float4*)&op[jb * 4] = make_float4(vals[jb * 4 + 0], vals[jb * 4 + 1],
                                            vals[jb * 4 + 2], vals[jb * 4 + 3]);
    }
  }
}

// ---- fused feature attention + residual + LN2, one block per (b,e) ----
__global__ __launch_bounds__(256) void attn_kernel(
    const short* __restrict__ q, const short* __restrict__ k,
    const short* __restrict__ v, const float* __restrict__ x,
    const float* __restrict__ wn_g, const float* __restrict__ wn_b,
    const float* __restrict__ ln2_g, const float* __restrict__ ln2_b,
    float* __restrict__ x1, short* __restrict__ h2) {
  __shared__ float att_s[64][68];
  const int t = threadIdx.x;
  const int wave = t >> 6, lane = t & 63;
  const int lr = lane & 15, g = lane >> 4;
  const long base = (long)blockIdx.x * 64;
  const long qoff = base * D_DIM;

  const f32x4 vzero = {0.f, 0.f, 0.f, 0.f};
  f32x4 acc[4];
#pragma unroll
  for (int nt = 0; nt < 4; ++nt) acc[nt] = vzero;

  for (int ks = 0; ks < 16; ++ks) {
    const int kc = ks * 32 + g * 8;
    bf16x8 afr = *(const bf16x8*)&q[qoff + (long)(wave * 16 + lr) * D_DIM + kc];
#pragma unroll
    for (int nt = 0; nt < 4; ++nt) {
      bf16x8 bfr = *(const bf16x8*)&k[qoff + (long)(nt * 16 + lr) * D_DIM + kc];
      acc[nt] = __builtin_amdgcn_mfma_f32_16x16x32_bf16(afr, bfr, acc[nt], 0, 0, 0);
    }
  }

  const float scale = 0.044194173824159216f;  // 1/sqrt(512)
#pragma unroll
  for (int r = 0; r < 4; ++r) {
    float s = 0.f, ss = 0.f;
#pragma unroll
    for (int nt = 0; nt < 4; ++nt) { float e = acc[nt][r]; s += e; ss += e * e; }
#pragma unroll
    for (int m = 1; m < 16; m <<= 1) { s += __shfl_xor(s, m); ss += __shfl_xor(ss, m); }
    float mean = s * (1.f / 64);
    float var  = ss * (1.f / 64) - mean * mean;
    float rstd = rsqrtf(var + 1e-5f);
    float e[4]; float mx = -1e30f;
#pragma unroll
    for (int nt = 0; nt < 4; ++nt) {
      int col = nt * 16 + lr;
      e[nt] = ((acc[nt][r] - mean) * rstd * wn_g[col] + wn_b[col]) * scale;
      mx = fmaxf(mx, e[nt]);
    }
#pragma unroll
    for (int m = 1; m < 16; m <<= 1) mx = fmaxf(mx, __shfl_xor(mx, m));
    float se = 0.f;
#pragma unroll
    for (int nt = 0; nt < 4; ++nt) { e[nt] = expf(e[nt] - mx); se += e[nt]; }
#pragma unroll
    for (int m = 1; m < 16; m <<= 1) se += __shfl_xor(se, m);
    float inv = 1.f / se;
#pragma unroll
    for (int nt = 0; nt < 4; ++nt)
      att_s[wave * 16 + 4 * g + r][nt * 16 + lr] = e[nt] * inv;
  }
  __syncthreads();

  const int d0 = lane * 8;
  float accp[16][8];
#pragma unroll
  for (int qi = 0; qi < 16; ++qi)
#pragma unroll
    for (int j = 0; j < 8; ++j) accp[qi][j] = 0.f;

  for (int kk0 = 0; kk0 < 64; kk0 += 4) {
    float vf[4][8];
#pragma unroll
    for (int kc = 0; kc < 4; ++kc) {
      bf16x8 vv = *(const bf16x8*)&v[qoff + (long)(kk0 + kc) * D_DIM + d0];
#pragma unroll
      for (int j = 0; j < 8; ++j) vf[kc][j] = bf2f(vv[j]);
    }
#pragma unroll
    for (int qi = 0; qi < 16; ++qi) {
      float4 a4 = *(const float4*)&att_s[wave * 16 + qi][kk0];
#pragma unroll
      for (int j = 0; j < 8; ++j) {
        accp[qi][j] += a4.x * vf[0][j];
        accp[qi][j] += a4.y * vf[1][j];
        accp[qi][j] += a4.z * vf[2][j];
        accp[qi][j] += a4.w * vf[3][j];
      }
    }
  }

  float g2v[8], b2v[8];
#pragma unroll
  for (int j = 0; j < 8; ++j) { g2v[j] = ln2_g[d0 + j]; b2v[j] = ln2_b[d0 + j]; }

#pragma unroll
  for (int qi = 0; qi < 16; ++qi) {
    const long row = base + wave * 16 + qi;
    const float* xr = x + row * D_DIM + d0;
    float4 x0 = *(const float4*)xr;
    float4 xb = *(const float4*)(xr + 4);
    accp[qi][0] += x0.x; accp[qi][1] += x0.y;
    accp[qi][2] += x0.z; accp[qi][3] += x0.w;
    accp[qi][4] += xb.x; accp[qi][5] += xb.y;
    accp[qi][6] += xb.z; accp[qi][7] += xb.w;
    float* po = x1 + row * D_DIM + d0;
    *(float4*)po       = make_float4(accp[qi][0], accp[qi][1], accp[qi][2], accp[qi][3]);
    *(float4*)(po + 4) = make_float4(accp[qi][4], accp[qi][5], accp[qi][6], accp[qi][7]);
    float s = 0.f, ss = 0.f;
#pragma unroll
    for (int j = 0; j < 8; ++j) { s += accp[qi][j]; ss += accp[qi][j] * accp[qi][j]; }
#pragma unroll
    for (int m = 1; m < 64; m <<= 1) { s += __shfl_xor(s, m); ss += __shfl_xor(ss, m); }
    float mean = s * (1.f / D_DIM);
    float var  = ss * (1.f / D_DIM) - mean * mean;
    float rstd = rsqrtf(var + 1e-5f);
    union { short sh[8]; int4 v; } o;
#pragma unroll
    for (int j = 0; j < 8; ++j)
      o.sh[j] = f2bf((accp[qi][j] - mean) * rstd * g2v[j] + b2v[j]);
    *(int4*)&h2[row * D_DIM + d0] = o.v;
  }
}

extern "C" void kernel_launch(void* const* d_in, const int* in_sizes, int n_in,
                              void* d_out, int out_size, void* d_ws, size_t ws_size,
                              hipStream_t stream) {
  (void)in_sizes; (void)n_in; (void)out_size; (void)ws_size;
  const float* x     = (const float*)d_in[0];
  const float* ln1_g = (const float*)d_in[1];
  const float* ln1_b = (const float*)d_in[2];
  const float* Wq    = (const float*)d_in[3];
  const float* bq    = (const float*)d_in[4];
  const float* Wk    = (const float*)d_in[5];
  const float* bk    = (const float*)d_in[6];
  const float* Wv    = (const float*)d_in[7];
  const float* bv    = (const float*)d_in[8];
  const float* wn_g  = (const float*)d_in[9];
  const float* wn_b  = (const float*)d_in[10];
  const float* ln2_g = (const float*)d_in[11];
  const float* ln2_b = (const float*)d_in[12];
  const float* W1    = (const float*)d_in[13];
  const float* b1    = (const float*)d_in[14];
  const float* W2    = (const float*)d_in[15];
  const float* b2    = (const float*)d_in[16];
  float* out = (float*)d_out;

  char* ws = (char*)d_ws;
  short* h   = (short*)(ws);                                  // 32 MB (h, then h2)
  short* qb  = (short*)(ws + (size_t)32  * 1024 * 1024);      // 32 MB
  short* kb  = (short*)(ws + (size_t)64  * 1024 * 1024);      // 32 MB
  short* vb  = (short*)(ws + (size_t)96  * 1024 * 1024);      // 32 MB
  short* ff1 = (short*)(ws + (size_t)32  * 1024 * 1024);      // 128 MB, aliases dead q/k/v
  short* Wqt = (short*)(ws + (size_t)160 * 1024 * 1024);      // [1536][512] contiguous qkv
  short* Wkt = Wqt + 512 * 512;
  short* Wvt = Wkt + 512 * 512;
  short* W1t = Wvt + 512 * 512;                               // [2048][512]
  short* W2t = W1t + 512 * 2048;                              // [512][2048]

  const size_t lds_bytes = 3 * 8192 * 2 * 2;                  // 98304 B
  (void)hipFuncSetAttribute((const void*)gemm256<1, 0>,
      hipFuncAttributeMaxDynamicSharedMemorySize, (int)lds_bytes);
  (void)hipFuncSetAttribute((const void*)gemm256<0, 1>,
      hipFuncAttributeMaxDynamicSharedMemorySize, (int)lds_bytes);

  wconvT<<<dim3(512 / 32, 512 / 32),  256, 0, stream>>>(Wq, Wqt, 512, 512);
  wconvT<<<dim3(512 / 32, 512 / 32),  256, 0, stream>>>(Wk, Wkt, 512, 512);
  wconvT<<<dim3(512 / 32, 512 / 32),  256, 0, stream>>>(Wv, Wvt, 512, 512);
  wconvT<<<dim3(2048 / 32, 512 / 32), 256, 0, stream>>>(W1, W1t, 512, 2048);
  wconvT<<<dim3(512 / 32, 2048 / 32), 256, 0, stream>>>(W2, W2t, 2048, 512);

  ln_kernel<<<NROWS / 4, 256, 0, stream>>>(x, ln1_g, ln1_b, h);

  dim3 gqkv(1536 / 256, NROWS / 256);   // (6, 128) = 768 blocks
  gemm256<1, 0><<<gqkv, 512, lds_bytes, stream>>>(h, Wqt, bq, bk, bv,
                                                  qb, kb, vb, nullptr, 512, 512);

  attn_kernel<<<NBE, 256, 0, stream>>>(qb, kb, vb, x, wn_g, wn_b,
                                       ln2_g, ln2_b, out, h);

  dim3 gff1(2048 / 256, NROWS / 256);   // (8, 128) = 1024 blocks
  gemm256<1, 0><<<gff1, 512, lds_bytes, stream>>>(h, W1t, b1, b1, b1,
                                                  ff1, ff1, ff1, nullptr, 512, 2048);

  dim3 gff2(512 / 256, NROWS / 256);    // (2, 128) = 256 blocks
  gemm256<0, 1><<<gff2, 512, lds_bytes, stream>>>(ff1, W2t, b2, b2, b2,
                                                  out, out, out, out, 2048, 512);
}

// Round 7
// 496.359 us; speedup vs baseline: 1.3006x; 1.0231x over previous
//
#include <hip/hip_runtime.h>
#include <hip/hip_bf16.h>

// FeatureAttention on MI355X — Round 7: 256x256 BK=64 GEMM, 128KB LDS dbuf,
// row-major + T2 XOR-swizzle LDS layout (both-sides, rule #21): staging loads
// are contiguous 128B per row (DRAM row locality for the FFN2 A-stream),
// frag ds_reads <=2-way bank aliasing. Schedule = catalog 2-phase recipe.
// Pipeline: wconvT(x5) -> LN1 -> fused QKV GEMM -> attn(+LN2) -> FFN1 -> FFN2.

#define D_DIM 512
#define NROWS 32768
#define NBE   512

typedef __attribute__((ext_vector_type(8))) short bf16x8;
typedef __attribute__((ext_vector_type(4))) float f32x4;

typedef const __attribute__((address_space(1))) unsigned g_u32;
typedef __attribute__((address_space(3))) unsigned lds_u32;

__device__ __forceinline__ short f2bf(float f) {
  union { float f; unsigned u; } c; c.f = f;
  unsigned u = c.u;
  unsigned r = (u + 0x7FFFu + ((u >> 16) & 1u)) >> 16;   // RNE
  return (short)r;
}
__device__ __forceinline__ float bf2f(short s) {
  union { unsigned u; float f; } c; c.u = ((unsigned)(unsigned short)s) << 16;
  return c.f;
}

// ---- LDS-tiled transpose + fp32->bf16: Wt[n][k] = bf16(W[k][n]) ----
__global__ __launch_bounds__(256) void wconvT(const float* __restrict__ W,
                                              short* __restrict__ Wt,
                                              int K, int N) {
  __shared__ float tile[32][33];
  const int t = threadIdx.x;
  const int r  = t >> 3;            // 0..31
  const int c4 = (t & 7) * 4;       // 0,4,...,28
  const long k0 = (long)blockIdx.y * 32;
  const long n0 = (long)blockIdx.x * 32;
  float4 v = *(const float4*)&W[(k0 + r) * N + n0 + c4];
  tile[r][c4 + 0] = v.x; tile[r][c4 + 1] = v.y;
  tile[r][c4 + 2] = v.z; tile[r][c4 + 3] = v.w;
  __syncthreads();
  union { short sh[4]; int2 v; } o;
#pragma unroll
  for (int j = 0; j < 4; ++j) o.sh[j] = f2bf(tile[c4 + j][r]);
  *(int2*)&Wt[(n0 + r) * K + k0 + c4] = o.v;
}

// ---- LayerNorm over D=512, fp32 in -> bf16 out. One wave per row. ----
__global__ __launch_bounds__(256) void ln_kernel(const float* __restrict__ x,
                                                 const float* __restrict__ gam,
                                                 const float* __restrict__ bet,
                                                 short* __restrict__ h) {
  const int t = threadIdx.x;
  const long row = (long)blockIdx.x * 4 + (t >> 6);
  const int lane = t & 63;
  const float* xr = x + row * D_DIM + lane * 8;
  float4 a = *(const float4*)xr;
  float4 b = *(const float4*)(xr + 4);
  float xs[8] = {a.x, a.y, a.z, a.w, b.x, b.y, b.z, b.w};
  float s = 0.f, ss = 0.f;
#pragma unroll
  for (int j = 0; j < 8; ++j) { s += xs[j]; ss += xs[j] * xs[j]; }
#pragma unroll
  for (int m = 1; m < 64; m <<= 1) {
    s  += __shfl_xor(s, m);
    ss += __shfl_xor(ss, m);
  }
  float mean = s * (1.f / D_DIM);
  float var  = ss * (1.f / D_DIM) - mean * mean;
  float rstd = rsqrtf(var + 1e-5f);
  union { short sh[8]; int4 v; } o;
#pragma unroll
  for (int j = 0; j < 8; ++j) {
    int d = lane * 8 + j;
    o.sh[j] = f2bf((xs[j] - mean) * rstd * gam[d] + bet[d]);
  }
  *(int4*)&h[row * D_DIM + lane * 8] = o.v;
}

// ---- 256x256 BK=64 bf16 MFMA GEMM, XOR-swizzled LDS, 2-phase dbuf ----
// out[M,N] = A[M,K] @ Bt[N,K]^T + bias (+resid). 512 threads = 8 waves (2x4),
// wave owns 128x64 = 8x4 frags, K=64/tile -> 64 MFMA/wave/tile.
// LDS slab (A or B): [256 rows][128B], swizzled byte(row,kb)=row*128 +
// (kb ^ ((row&7)<<4)). Staged with pre-swizzled global source (rule #21):
// wave w, load i (0..3), lane l -> row = w*32+i*8+(l>>3), global k-byte
// 16*((l&7)^(l>>3&7)) within the row's 128B slice; LDS dest = linear
// w*4KB+i*1KB+l*16 == row*128 + swz(kb) by construction.
// Frag ds_read: addr = row*128 + ((t*64+g*16)^((row&7)<<4)) -> rows r,r+8
// share a 16B slot => 2-way bank aliasing (free, m136).
// Schedule (T3 minimum 2-phase recipe): STAGE(buf^1, t+1); ds_read+MFMA on
// buf[cur] (compiler-scheduled lgkmcnt); __syncthreads() (vm+lgkm drain).
template <int OUT_BF16, int RESID>
__global__ __launch_bounds__(512) void gemm256(
    const short* __restrict__ A, const short* __restrict__ Bt,
    const float* __restrict__ bias0, const float* __restrict__ bias1,
    const float* __restrict__ bias2,
    void* __restrict__ out0, void* __restrict__ out1, void* __restrict__ out2,
    const float* __restrict__ resid, int K, int nsplit) {
  extern __shared__ short smem[];     // 2 x (A 16384 + B 16384) shorts
  short* As = smem;                   // slab stride 16384 shorts (32KB)
  short* Bs = smem + 2 * 16384;

  const int t = threadIdx.x;
  const int wave = t >> 6, lane = t & 63;
  const int lr = lane & 15, g = lane >> 4;
  const int wr = wave >> 2, wc = wave & 3;   // 2 x 4 wave grid

  // XCD-chunked bijective swizzle (T1); nwg % 8 == 0 for all our grids.
  const int gx = gridDim.x;
  const int nwg = gx * gridDim.y;
  const int hid = blockIdx.y * gx + blockIdx.x;
  const int lid = (hid & 7) * (nwg >> 3) + (hid >> 3);
  const int m0 = (lid / gx) * 256;
  const int n0 = (lid % gx) * 256;

  const int seg = n0 / nsplit;               // block-uniform
  const int ncol0 = n0 - seg * nsplit;
  const float* bias = seg == 0 ? bias0 : (seg == 1 ? bias1 : bias2);
  void* outp = seg == 0 ? out0 : (seg == 1 ? out1 : out2);

  // staging addresses: wave w owns rows w*32..w*32+31 of A and of B.
  // lane l -> row_off = (l>>3), swizzled k-shorts 8*((l&7)^(l>>3&7))
  const int srow = lane >> 3;                 // 0..7
  const int skel = 8 * ((lane & 7) ^ srow);   // swizzled k-elem offset
  const short* gA0 = &A[(long)(m0 + wave * 32 + srow) * K + skel];
  const short* gB0 = &Bt[(long)(n0 + wave * 32 + srow) * K + skel];
  const long rstep8 = 8L * K;                 // +8 rows

#define STAGE(bufi, kk)                                                        \
  do {                                                                         \
    _Pragma("unroll")                                                          \
    for (int i = 0; i < 4; ++i) {                                              \
      __builtin_amdgcn_global_load_lds((g_u32*)(gA0 + i * rstep8 + (kk)),      \
          (lds_u32*)(As + (bufi) * 16384 + wave * 2048 + i * 512 + lane * 8),  \
          16, 0, 0);                                                           \
      __builtin_amdgcn_global_load_lds((g_u32*)(gB0 + i * rstep8 + (kk)),      \
          (lds_u32*)(Bs + (bufi) * 16384 + wave * 2048 + i * 512 + lane * 8),  \
          16, 0, 0);                                                           \
    }                                                                          \
  } while (0)

  f32x4 acc[8][4];
  const f32x4 vzero = {0.f, 0.f, 0.f, 0.f};
#pragma unroll
  for (int mi = 0; mi < 8; ++mi)
#pragma unroll
    for (int ni = 0; ni < 4; ++ni) acc[mi][ni] = vzero;

  const int nt = K >> 6;                      // K-tiles of 64
  STAGE(0, 0);
  __syncthreads();                            // drain + barrier

  // frag read offsets (shorts): row*64 + ((t32*32 + g*8) ^ ((row&7)*8))
  const int fswz = (lr & 7) * 8;              // lane-const swizzle term
  int cur = 0;
  for (int T = 0; T < nt; ++T) {
    if (T + 1 < nt) STAGE(cur ^ 1, (T + 1) * 64);
    const short* sA = As + cur * 16384;
    const short* sB = Bs + cur * 16384;
    bf16x8 af[8][2], bfr[4][2];
#pragma unroll
    for (int c = 0; c < 8; ++c) {
      const int rbase = (wr * 128 + c * 16 + lr) * 64;
#pragma unroll
      for (int t2 = 0; t2 < 2; ++t2)
        af[c][t2] = *(const bf16x8*)&sA[rbase + ((t2 * 32 + g * 8) ^ fswz)];
    }
#pragma unroll
    for (int c = 0; c < 4; ++c) {
      const int rbase = (wc * 64 + c * 16 + lr) * 64;
#pragma unroll
      for (int t2 = 0; t2 < 2; ++t2)
        bfr[c][t2] = *(const bf16x8*)&sB[rbase + ((t2 * 32 + g * 8) ^ fswz)];
    }
#pragma unroll
    for (int t2 = 0; t2 < 2; ++t2)
#pragma unroll
      for (int mi = 0; mi < 8; ++mi)
#pragma unroll
        for (int ni = 0; ni < 4; ++ni)
          acc[mi][ni] = __builtin_amdgcn_mfma_f32_16x16x32_bf16(
              af[mi][t2], bfr[ni][t2], acc[mi][ni], 0, 0, 0);
    __syncthreads();                          // drain vm+lgkm, swap
    cur ^= 1;
  }
#undef STAGE

  // ---- epilogue: LDS-transpose to row-major vectorized stores ----
  float* cs = (float*)smem + wave * 1088;    // wave-private 16 x 68 f32
  float bv[4];
#pragma unroll
  for (int ni = 0; ni < 4; ++ni) bv[ni] = bias[ncol0 + wc * 64 + ni * 16 + lr];
  const int er = lane >> 2;                  // 0..15: row within 16-row group
  const int ec = (lane & 3) * 16;            // col block within 64

#pragma unroll
  for (int mi = 0; mi < 8; ++mi) {
#pragma unroll
    for (int ni = 0; ni < 4; ++ni)
#pragma unroll
      for (int r = 0; r < 4; ++r)
        cs[(g * 4 + r) * 68 + ni * 16 + lr] = acc[mi][ni][r] + bv[ni];
    const long grow = m0 + wr * 128 + mi * 16 + er;
    const long gcol = ncol0 + wc * 64 + ec;
    float vals[16];
#pragma unroll
    for (int jb = 0; jb < 4; ++jb) {
      float4 v = *(const float4*)&cs[er * 68 + ec + jb * 4];
      vals[jb * 4 + 0] = v.x; vals[jb * 4 + 1] = v.y;
      vals[jb * 4 + 2] = v.z; vals[jb * 4 + 3] = v.w;
    }
    if (RESID) {
      const float* rp = resid + grow * (long)nsplit + gcol;
#pragma unroll
      for (int jb = 0; jb < 4; ++jb) {
        float4 v = *(const float4*)&rp[jb * 4];
        vals[jb * 4 + 0] += v.x; vals[jb * 4 + 1] += v.y;
        vals[jb * 4 + 2] += v.z; vals[jb * 4 + 3] += v.w;
      }
    }
    if (OUT_BF16) {
      union { short sh[16]; int4 q[2]; } o;
#pragma unroll
      for (int j = 0; j < 16; ++j) o.sh[j] = f2bf(vals[j]);
      short* op = (short*)outp + grow * (long)nsplit + gcol;
      *(int4*)op = o.q[0];
      *(int4*)(op + 8) = o.q[1];
    } else {
      float* op = (float*)outp + grow * (long)nsplit + gcol;
#pragma unroll
      for (int jb = 0; jb < 4; ++jb)
        *(float4*)&op[jb * 4] = make_float4(vals[jb * 4 + 0], vals[jb * 4 + 1],
                                            vals[jb * 4 + 2], vals[jb * 4 + 3]);
    }
  }
}

// ---- fused feature attention + residual + LN2, one block per (b,e) ----
__global__ __launch_bounds__(256) void attn_kernel(
    const short* __restrict__ q, const short* __restrict__ k,
    const short* __restrict__ v, const float* __restrict__ x,
    const float* __restrict__ wn_g, const float* __restrict__ wn_b,
    const float* __restrict__ ln2_g, const float* __restrict__ ln2_b,
    float* __restrict__ x1, short* __restrict__ h2) {
  __shared__ float att_s[64][68];
  const int t = threadIdx.x;
  const int wave = t >> 6, lane = t & 63;
  const int lr = lane & 15, g = lane >> 4;
  const long base = (long)blockIdx.x * 64;
  const long qoff = base * D_DIM;

  const f32x4 vzero = {0.f, 0.f, 0.f, 0.f};
  f32x4 acc[4];
#pragma unroll
  for (int nt = 0; nt < 4; ++nt) acc[nt] = vzero;

  for (int ks = 0; ks < 16; ++ks) {
    const int kc = ks * 32 + g * 8;
    bf16x8 afr = *(const bf16x8*)&q[qoff + (long)(wave * 16 + lr) * D_DIM + kc];
#pragma unroll
    for (int nt = 0; nt < 4; ++nt) {
      bf16x8 bfr = *(const bf16x8*)&k[qoff + (long)(nt * 16 + lr) * D_DIM + kc];
      acc[nt] = __builtin_amdgcn_mfma_f32_16x16x32_bf16(afr, bfr, acc[nt], 0, 0, 0);
    }
  }

  const float scale = 0.044194173824159216f;  // 1/sqrt(512)
#pragma unroll
  for (int r = 0; r < 4; ++r) {
    float s = 0.f, ss = 0.f;
#pragma unroll
    for (int nt = 0; nt < 4; ++nt) { float e = acc[nt][r]; s += e; ss += e * e; }
#pragma unroll
    for (int m = 1; m < 16; m <<= 1) { s += __shfl_xor(s, m); ss += __shfl_xor(ss, m); }
    float mean = s * (1.f / 64);
    float var  = ss * (1.f / 64) - mean * mean;
    float rstd = rsqrtf(var + 1e-5f);
    float e[4]; float mx = -1e30f;
#pragma unroll
    for (int nt = 0; nt < 4; ++nt) {
      int col = nt * 16 + lr;
      e[nt] = ((acc[nt][r] - mean) * rstd * wn_g[col] + wn_b[col]) * scale;
      mx = fmaxf(mx, e[nt]);
    }
#pragma unroll
    for (int m = 1; m < 16; m <<= 1) mx = fmaxf(mx, __shfl_xor(mx, m));
    float se = 0.f;
#pragma unroll
    for (int nt = 0; nt < 4; ++nt) { e[nt] = expf(e[nt] - mx); se += e[nt]; }
#pragma unroll
    for (int m = 1; m < 16; m <<= 1) se += __shfl_xor(se, m);
    float inv = 1.f / se;
#pragma unroll
    for (int nt = 0; nt < 4; ++nt)
      att_s[wave * 16 + 4 * g + r][nt * 16 + lr] = e[nt] * inv;
  }
  __syncthreads();

  const int d0 = lane * 8;
  float accp[16][8];
#pragma unroll
  for (int qi = 0; qi < 16; ++qi)
#pragma unroll
    for (int j = 0; j < 8; ++j) accp[qi][j] = 0.f;

  for (int kk0 = 0; kk0 < 64; kk0 += 4) {
    float vf[4][8];
#pragma unroll
    for (int kc = 0; kc < 4; ++kc) {
      bf16x8 vv = *(const bf16x8*)&v[qoff + (long)(kk0 + kc) * D_DIM + d0];
#pragma unroll
      for (int j = 0; j < 8; ++j) vf[kc][j] = bf2f(vv[j]);
    }
#pragma unroll
    for (int qi = 0; qi < 16; ++qi) {
      float4 a4 = *(const float4*)&att_s[wave * 16 + qi][kk0];
#pragma unroll
      for (int j = 0; j < 8; ++j) {
        accp[qi][j] += a4.x * vf[0][j];
        accp[qi][j] += a4.y * vf[1][j];
        accp[qi][j] += a4.z * vf[2][j];
        accp[qi][j] += a4.w * vf[3][j];
      }
    }
  }

  float g2v[8], b2v[8];
#pragma unroll
  for (int j = 0; j < 8; ++j) { g2v[j] = ln2_g[d0 + j]; b2v[j] = ln2_b[d0 + j]; }

#pragma unroll
  for (int qi = 0; qi < 16; ++qi) {
    const long row = base + wave * 16 + qi;
    const float* xr = x + row * D_DIM + d0;
    float4 x0 = *(const float4*)xr;
    float4 xb = *(const float4*)(xr + 4);
    accp[qi][0] += x0.x; accp[qi][1] += x0.y;
    accp[qi][2] += x0.z; accp[qi][3] += x0.w;
    accp[qi][4] += xb.x; accp[qi][5] += xb.y;
    accp[qi][6] += xb.z; accp[qi][7] += xb.w;
    float* po = x1 + row * D_DIM + d0;
    *(float4*)po       = make_float4(accp[qi][0], accp[qi][1], accp[qi][2], accp[qi][3]);
    *(float4*)(po + 4) = make_float4(accp[qi][4], accp[qi][5], accp[qi][6], accp[qi][7]);
    float s = 0.f, ss = 0.f;
#pragma unroll
    for (int j = 0; j < 8; ++j) { s += accp[qi][j]; ss += accp[qi][j] * accp[qi][j]; }
#pragma unroll
    for (int m = 1; m < 64; m <<= 1) { s += __shfl_xor(s, m); ss += __shfl_xor(ss, m); }
    float mean = s * (1.f / D_DIM);
    float var  = ss * (1.f / D_DIM) - mean * mean;
    float rstd = rsqrtf(var + 1e-5f);
    union { short sh[8]; int4 v; } o;
#pragma unroll
    for (int j = 0; j < 8; ++j)
      o.sh[j] = f2bf((accp[qi][j] - mean) * rstd * g2v[j] + b2v[j]);
    *(int4*)&h2[row * D_DIM + d0] = o.v;
  }
}

extern "C" void kernel_launch(void* const* d_in, const int* in_sizes, int n_in,
                              void* d_out, int out_size, void* d_ws, size_t ws_size,
                              hipStream_t stream) {
  (void)in_sizes; (void)n_in; (void)out_size; (void)ws_size;
  const float* x     = (const float*)d_in[0];
  const float* ln1_g = (const float*)d_in[1];
  const float* ln1_b = (const float*)d_in[2];
  const float* Wq    = (const float*)d_in[3];
  const float* bq    = (const float*)d_in[4];
  const float* Wk    = (const float*)d_in[5];
  const float* bk    = (const float*)d_in[6];
  const float* Wv    = (const float*)d_in[7];
  const float* bv    = (const float*)d_in[8];
  const float* wn_g  = (const float*)d_in[9];
  const float* wn_b  = (const float*)d_in[10];
  const float* ln2_g = (const float*)d_in[11];
  const float* ln2_b = (const float*)d_in[12];
  const float* W1    = (const float*)d_in[13];
  const float* b1    = (const float*)d_in[14];
  const float* W2    = (const float*)d_in[15];
  const float* b2    = (const float*)d_in[16];
  float* out = (float*)d_out;

  char* ws = (char*)d_ws;
  short* h   = (short*)(ws);                                  // 32 MB (h, then h2)
  short* qb  = (short*)(ws + (size_t)32  * 1024 * 1024);      // 32 MB
  short* kb  = (short*)(ws + (size_t)64  * 1024 * 1024);      // 32 MB
  short* vb  = (short*)(ws + (size_t)96  * 1024 * 1024);      // 32 MB
  short* ff1 = (short*)(ws + (size_t)32  * 1024 * 1024);      // 128 MB, aliases dead q/k/v
  short* Wqt = (short*)(ws + (size_t)160 * 1024 * 1024);      // [1536][512] contiguous qkv
  short* Wkt = Wqt + 512 * 512;
  short* Wvt = Wkt + 512 * 512;
  short* W1t = Wvt + 512 * 512;                               // [2048][512]
  short* W2t = W1t + 512 * 2048;                              // [512][2048]

  const size_t lds_bytes = 4 * 16384 * 2;                     // 131072 B
  (void)hipFuncSetAttribute((const void*)gemm256<1, 0>,
      hipFuncAttributeMaxDynamicSharedMemorySize, (int)lds_bytes);
  (void)hipFuncSetAttribute((const void*)gemm256<0, 1>,
      hipFuncAttributeMaxDynamicSharedMemorySize, (int)lds_bytes);

  wconvT<<<dim3(512 / 32, 512 / 32),  256, 0, stream>>>(Wq, Wqt, 512, 512);
  wconvT<<<dim3(512 / 32, 512 / 32),  256, 0, stream>>>(Wk, Wkt, 512, 512);
  wconvT<<<dim3(512 / 32, 512 / 32),  256, 0, stream>>>(Wv, Wvt, 512, 512);
  wconvT<<<dim3(2048 / 32, 512 / 32), 256, 0, stream>>>(W1, W1t, 512, 2048);
  wconvT<<<dim3(512 / 32, 2048 / 32), 256, 0, stream>>>(W2, W2t, 2048, 512);

  ln_kernel<<<NROWS / 4, 256, 0, stream>>>(x, ln1_g, ln1_b, h);

  dim3 gqkv(1536 / 256, NROWS / 256);   // (6, 128) = 768 blocks
  gemm256<1, 0><<<gqkv, 512, lds_bytes, stream>>>(h, Wqt, bq, bk, bv,
                                                  qb, kb, vb, nullptr, 512, 512);

  attn_kernel<<<NBE, 256, 0, stream>>>(qb, kb, vb, x, wn_g, wn_b,
                                       ln2_g, ln2_b, out, h);

  dim3 gff1(2048 / 256, NROWS / 256);   // (8, 128) = 1024 blocks
  gemm256<1, 0><<<gff1, 512, lds_bytes, stream>>>(h, W1t, b1, b1, b1,
                                                  ff1, ff1, ff1, nullptr, 512, 2048);

  dim3 gff2(512 / 256, NROWS / 256);    // (2, 128) = 256 blocks
  gemm256<0, 1><<<gff2, 512, lds_bytes, stream>>>(ff1, W2t, b2, b2, b2,
                                                  out, out, out, out, 2048, 512);
}